// Round 1
// baseline (941.194 us; speedup 1.0000x reference)
//
#include <hip/hip_runtime.h>
#include <math.h>

#define NB 1024
#define NM 50
#define NH 128
#define NI 100000

// flat output offsets (return order)
constexpr size_t OFF_H   = (size_t)NB * NI;              // h_new[None]  (1,B,H)
constexpr size_t OFF_EMB = OFF_H   + (size_t)NB * NH;    // embedded_input (B,1,E)
constexpr size_t OFF_GRU = OFF_EMB + (size_t)NB * NH;    // gru_output (B,1,H)
constexpr size_t OFF_ATT = OFF_GRU + (size_t)NB * NH;    // attn_weights (B,M)

__device__ __forceinline__ float sigmoidf_(float x) { return 1.0f / (1.0f + expf(-x)); }

// ---------------- Kernel 1: attention (per-batch) ----------------
// block = 1 batch, 128 threads (2 waves). Thread t owns output column h'=t.
__global__ __launch_bounds__(128) void attn_kernel(
    const float* __restrict__ hidden,     // (1,B,H)
    const float* __restrict__ inter,      // (B,M,H)
    const int*   __restrict__ user_list,  // (B,)
    const float* __restrict__ cat_W,      // (U,H,2H)
    const float* __restrict__ cat_b,      // (U,H)
    const float* __restrict__ scale_W,    // (U,1,H)
    float* __restrict__ attn_out,         // (B,M)
    float* __restrict__ context)          // (B,H) scratch
{
    const int b = blockIdx.x;
    const int t = threadIdx.x;

    __shared__ float hid[NH];
    __shared__ float itT[NH][56];   // transposed inter tile [h][m], pad 56 (16B-aligned rows)
    __shared__ float e_sm[64];
    __shared__ float attn_sm[64];

    const int u = user_list[b];

    hid[t] = hidden[b * NH + t];
    for (int idx = t; idx < NM * NH; idx += 128) {
        int m = idx >> 7, j = idx & 127;
        itT[j][m] = inter[(size_t)b * NM * NH + idx];
    }
    // zero the m-padding so the tail tile is benign
    #pragma unroll
    for (int m = NM; m < 56; ++m) itT[t][m] = 0.0f;
    if (t < 64) e_sm[t] = 0.0f;
    __syncthreads();

    // per-thread row of Wc: cat_W[u][t][0:256]
    const float* wrow = cat_W + ((size_t)u * NH + t) * (2 * NH);
    float acc_a = cat_b[(size_t)u * NH + t];
    #pragma unroll
    for (int i4 = 0; i4 < NH / 4; ++i4) {
        float4 w  = *(const float4*)(wrow + i4 * 4);
        float4 h4 = *(const float4*)(&hid[i4 * 4]);
        acc_a += w.x * h4.x + w.y * h4.y + w.z * h4.z + w.w * h4.w;
    }
    // hold the inter-half of the row in registers (reused across all 50 m)
    float wreg[NH];
    #pragma unroll
    for (int j4 = 0; j4 < NH / 4; ++j4) {
        float4 w = *(const float4*)(wrow + NH + j4 * 4);
        wreg[j4 * 4 + 0] = w.x; wreg[j4 * 4 + 1] = w.y;
        wreg[j4 * 4 + 2] = w.z; wreg[j4 * 4 + 3] = w.w;
    }
    const float wsc = scale_W[(size_t)u * NH + t];

    // energies: e[m] = sum_h wsc_h * tanh(acc_a_h + dot(inter[m,:], wreg_h))
    for (int m0 = 0; m0 < NM; m0 += 4) {
        float a0 = acc_a, a1 = acc_a, a2 = acc_a, a3 = acc_a;
        #pragma unroll
        for (int j = 0; j < NH; ++j) {
            float4 v = *(const float4*)(&itT[j][m0]);   // uniform addr -> LDS broadcast
            float  w = wreg[j];
            a0 = fmaf(w, v.x, a0); a1 = fmaf(w, v.y, a1);
            a2 = fmaf(w, v.z, a2); a3 = fmaf(w, v.w, a3);
        }
        float v0 = wsc * tanhf(a0), v1 = wsc * tanhf(a1);
        float v2 = wsc * tanhf(a2), v3 = wsc * tanhf(a3);
        #pragma unroll
        for (int s = 1; s < 64; s <<= 1) {
            v0 += __shfl_xor(v0, s); v1 += __shfl_xor(v1, s);
            v2 += __shfl_xor(v2, s); v3 += __shfl_xor(v3, s);
        }
        if ((t & 63) == 0) {
            atomicAdd(&e_sm[m0 + 0], v0); atomicAdd(&e_sm[m0 + 1], v1);
            atomicAdd(&e_sm[m0 + 2], v2); atomicAdd(&e_sm[m0 + 3], v3);
        }
    }
    __syncthreads();

    // softmax over m (wave 0 only); scale_b is a per-batch constant -> softmax-invariant, skipped
    if (t < 64) {
        float x = (t < NM) ? e_sm[t] : -INFINITY;
        float mx = x;
        #pragma unroll
        for (int s = 1; s < 64; s <<= 1) mx = fmaxf(mx, __shfl_xor(mx, s));
        float ex = (t < NM) ? expf(x - mx) : 0.0f;
        float sum = ex;
        #pragma unroll
        for (int s = 1; s < 64; s <<= 1) sum += __shfl_xor(sum, s);
        float a = ex / sum;
        attn_sm[t] = a;
        if (t < NM) attn_out[(size_t)b * NM + t] = a;
    }
    __syncthreads();

    // context[h] = sum_m attn[m] * inter[m][h]
    float c = 0.0f;
    #pragma unroll
    for (int m = 0; m < NM; ++m) c = fmaf(attn_sm[m], itT[t][m], c);
    context[(size_t)b * NH + t] = c;
}

// ---------------- Kernel 2: GRU cell (4 batches / block) ----------------
__global__ __launch_bounds__(128) void gru_kernel(
    const float* __restrict__ emb,      // (B,1,E)
    const float* __restrict__ hidden,   // (1,B,H)
    const float* __restrict__ context,  // (B,H)
    const float* __restrict__ w_ih,     // (3H, 2E)
    const float* __restrict__ w_hh,     // (3H, H)
    const float* __restrict__ b_ih,     // (3H,)
    const float* __restrict__ b_hh,     // (3H,)
    float* __restrict__ out_h,          // (B,H)
    float* __restrict__ out_emb,        // (B,E)
    float* __restrict__ out_gru)        // (B,H)
{
    const int b0 = blockIdx.x * 4;
    const int t  = threadIdx.x;   // h index 0..127

    __shared__ float x_sm[4][2 * NH];
    __shared__ float h_sm[4][NH];
    #pragma unroll
    for (int bb = 0; bb < 4; ++bb) {
        x_sm[bb][t]      = emb[(size_t)(b0 + bb) * NH + t];
        x_sm[bb][NH + t] = context[(size_t)(b0 + bb) * NH + t];
        h_sm[bb][t]      = hidden[(size_t)(b0 + bb) * NH + t];
    }
    __syncthreads();

    const float* wr = w_ih + (size_t)t * 256;
    const float* wz = w_ih + (size_t)(NH + t) * 256;
    const float* wn = w_ih + (size_t)(2 * NH + t) * 256;
    float gr[4], gz[4], gn[4];
    #pragma unroll
    for (int bb = 0; bb < 4; ++bb) { gr[bb] = b_ih[t]; gz[bb] = b_ih[NH + t]; gn[bb] = b_ih[2 * NH + t]; }
    for (int i4 = 0; i4 < 64; ++i4) {
        float4 wr4 = *(const float4*)(wr + i4 * 4);
        float4 wz4 = *(const float4*)(wz + i4 * 4);
        float4 wn4 = *(const float4*)(wn + i4 * 4);
        #pragma unroll
        for (int bb = 0; bb < 4; ++bb) {
            float4 x4 = *(const float4*)(&x_sm[bb][i4 * 4]);
            gr[bb] += wr4.x * x4.x + wr4.y * x4.y + wr4.z * x4.z + wr4.w * x4.w;
            gz[bb] += wz4.x * x4.x + wz4.y * x4.y + wz4.z * x4.z + wz4.w * x4.w;
            gn[bb] += wn4.x * x4.x + wn4.y * x4.y + wn4.z * x4.z + wn4.w * x4.w;
        }
    }
    const float* vr = w_hh + (size_t)t * NH;
    const float* vz = w_hh + (size_t)(NH + t) * NH;
    const float* vn = w_hh + (size_t)(2 * NH + t) * NH;
    float hr[4], hz[4], hn[4];
    #pragma unroll
    for (int bb = 0; bb < 4; ++bb) { hr[bb] = b_hh[t]; hz[bb] = b_hh[NH + t]; hn[bb] = b_hh[2 * NH + t]; }
    for (int i4 = 0; i4 < 32; ++i4) {
        float4 vr4 = *(const float4*)(vr + i4 * 4);
        float4 vz4 = *(const float4*)(vz + i4 * 4);
        float4 vn4 = *(const float4*)(vn + i4 * 4);
        #pragma unroll
        for (int bb = 0; bb < 4; ++bb) {
            float4 h4 = *(const float4*)(&h_sm[bb][i4 * 4]);
            hr[bb] += vr4.x * h4.x + vr4.y * h4.y + vr4.z * h4.z + vr4.w * h4.w;
            hz[bb] += vz4.x * h4.x + vz4.y * h4.y + vz4.z * h4.z + vz4.w * h4.w;
            hn[bb] += vn4.x * h4.x + vn4.y * h4.y + vn4.z * h4.z + vn4.w * h4.w;
        }
    }
    #pragma unroll
    for (int bb = 0; bb < 4; ++bb) {
        float r = sigmoidf_(gr[bb] + hr[bb]);
        float z = sigmoidf_(gz[bb] + hz[bb]);
        float n = tanhf(gn[bb] + r * hn[bb]);
        float h0 = h_sm[bb][t];
        float hnew = (1.0f - z) * n + z * h0;
        size_t o = (size_t)(b0 + bb) * NH + t;
        out_h[o]   = hnew;
        out_gru[o] = hnew;
        out_emb[o] = x_sm[bb][t];
    }
}

// ---------------- Kernel 3: output projection (fp32) ----------------
// block: 64 batches x 256 n-columns; thread owns one n, 64 batch accumulators.
__global__ __launch_bounds__(256) void out_kernel(
    const float* __restrict__ hnew,   // (B,H)
    const float* __restrict__ lin_W,  // (NI,H)
    const float* __restrict__ lin_b,  // (NI,)
    float* __restrict__ out)          // (B,NI)
{
    const int b0 = blockIdx.y * 64;
    const int n  = blockIdx.x * 256 + threadIdx.x;

    __shared__ float hnT[NH][68];   // [h][b], pad 68 (272B rows: 16B aligned)
    for (int idx = threadIdx.x; idx < 64 * NH; idx += 256) {
        int bb = idx >> 7, h = idx & 127;
        hnT[h][bb] = hnew[(size_t)(b0 + bb) * NH + h];
    }
    __syncthreads();

    const bool valid = (n < NI);
    const float* wrow = lin_W + (size_t)(valid ? n : 0) * NH;
    const float bias  = valid ? lin_b[n] : 0.0f;

    float acc[64];
    #pragma unroll
    for (int bb = 0; bb < 64; ++bb) acc[bb] = bias;

    for (int h4 = 0; h4 < NH / 4; ++h4) {
        float4 w4 = *(const float4*)(wrow + h4 * 4);
        float wv[4] = { w4.x, w4.y, w4.z, w4.w };
        #pragma unroll
        for (int hh = 0; hh < 4; ++hh) {
            const float w = wv[hh];
            const float* row = &hnT[h4 * 4 + hh][0];
            #pragma unroll
            for (int b4 = 0; b4 < 16; ++b4) {
                float4 v = *(const float4*)(row + b4 * 4);   // uniform addr -> broadcast
                acc[b4 * 4 + 0] = fmaf(w, v.x, acc[b4 * 4 + 0]);
                acc[b4 * 4 + 1] = fmaf(w, v.y, acc[b4 * 4 + 1]);
                acc[b4 * 4 + 2] = fmaf(w, v.z, acc[b4 * 4 + 2]);
                acc[b4 * 4 + 3] = fmaf(w, v.w, acc[b4 * 4 + 3]);
            }
        }
    }
    if (valid) {
        #pragma unroll
        for (int bb = 0; bb < 64; ++bb)
            out[(size_t)(b0 + bb) * NI + n] = acc[bb];
    }
}

extern "C" void kernel_launch(void* const* d_in, const int* in_sizes, int n_in,
                              void* d_out, int out_size, void* d_ws, size_t ws_size,
                              hipStream_t stream) {
    const float* emb      = (const float*)d_in[0];
    const float* hidden   = (const float*)d_in[1];
    const float* inter    = (const float*)d_in[2];
    // d_in[3] = delta_t_h : unused by the reference
    const int*   user     = (const int*)  d_in[4];
    const float* w_ih     = (const float*)d_in[5];
    const float* w_hh     = (const float*)d_in[6];
    const float* b_ih     = (const float*)d_in[7];
    const float* b_hh     = (const float*)d_in[8];
    const float* lin_W    = (const float*)d_in[9];
    const float* lin_b    = (const float*)d_in[10];
    const float* cat_W    = (const float*)d_in[11];
    const float* cat_b    = (const float*)d_in[12];
    const float* scale_W  = (const float*)d_in[13];
    // d_in[14] = scale_b : per-batch constant energy shift -> softmax invariant

    float* out = (float*)d_out;
    float* ctx = (float*)d_ws;   // (B,H) context scratch

    attn_kernel<<<NB, 128, 0, stream>>>(hidden, inter, user, cat_W, cat_b, scale_W,
                                        out + OFF_ATT, ctx);
    gru_kernel<<<NB / 4, 128, 0, stream>>>(emb, hidden, ctx, w_ih, w_hh, b_ih, b_hh,
                                           out + OFF_H, out + OFF_EMB, out + OFF_GRU);
    out_kernel<<<dim3((NI + 255) / 256, NB / 64), 256, 0, stream>>>(out + OFF_H, lin_W, lin_b, out);
}

// Round 2
// 343.562 us; speedup vs baseline: 2.7395x; 2.7395x over previous
//
#include <hip/hip_runtime.h>
#include <math.h>

#define NB 1024
#define NM 50
#define NH 128
#define NI 100000

// flat output offsets (return order)
constexpr size_t OFF_H   = (size_t)NB * NI;              // h_new[None]  (1,B,H)
constexpr size_t OFF_EMB = OFF_H   + (size_t)NB * NH;    // embedded_input (B,1,E)
constexpr size_t OFF_GRU = OFF_EMB + (size_t)NB * NH;    // gru_output (B,1,H)
constexpr size_t OFF_ATT = OFF_GRU + (size_t)NB * NH;    // attn_weights (B,M)

typedef __attribute__((ext_vector_type(8))) short bf16x8;
typedef __attribute__((ext_vector_type(4))) float f32x4;

static __device__ __forceinline__ unsigned short f2bf(float x) {
    unsigned int u = __float_as_uint(x);
    return (unsigned short)((u + 0x7FFFu + ((u >> 16) & 1u)) >> 16);   // RNE
}
static __device__ __forceinline__ float fast_tanh(float x) {
    float cx = fminf(fmaxf(x, -15.0f), 15.0f);
    float e = __expf(2.0f * cx);
    return (e - 1.0f) / (e + 1.0f);
}
static __device__ __forceinline__ float fast_sigmoid(float x) {
    float cx = fminf(fmaxf(x, -30.0f), 30.0f);
    return 1.0f / (1.0f + __expf(-cx));
}

// ---------------- Kernel 1: attention (per-batch) ----------------
// block = 1 batch, 128 threads. Thread t owns h-column t; acc[m] layout keeps
// VGPR ~85 (vs wreg[128] ~170+) so all 4 blocks/CU stay resident.
__global__ __launch_bounds__(128) void attn_kernel(
    const float* __restrict__ hidden,     // (1,B,H)
    const float* __restrict__ inter,      // (B,M,H)
    const int*   __restrict__ user_list,  // (B,)
    const float* __restrict__ cat_W,      // (U,H,2H)
    const float* __restrict__ cat_b,      // (U,H)
    const float* __restrict__ scale_W,    // (U,1,H)
    float* __restrict__ attn_out,         // (B,M)
    float* __restrict__ context)          // (B,H) scratch
{
    const int b = blockIdx.x;
    const int t = threadIdx.x;

    __shared__ float hid[NH];
    __shared__ float itT[NH][52];   // [h][m], 52 floats = 208B rows (16B aligned)
    __shared__ float e_sm[64];
    __shared__ float attn_sm[64];

    const int u = user_list[b];

    hid[t] = hidden[b * NH + t];
    for (int idx = t; idx < NM * NH; idx += 128) {
        int m = idx >> 7, j = idx & 127;
        itT[j][m] = inter[(size_t)b * NM * NH + idx];
    }
    itT[t][50] = 0.0f;
    itT[t][51] = 0.0f;
    if (t < 64) e_sm[t] = 0.0f;
    __syncthreads();

    // hidden-half dot + bias (same for all m)
    const float* wrow = cat_W + ((size_t)u * NH + t) * (2 * NH);
    float acc_a = cat_b[(size_t)u * NH + t];
    #pragma unroll
    for (int i4 = 0; i4 < NH / 4; ++i4) {
        float4 w  = *(const float4*)(wrow + i4 * 4);
        float4 h4 = *(const float4*)(&hid[i4 * 4]);
        acc_a += w.x * h4.x + w.y * h4.y + w.z * h4.z + w.w * h4.w;
    }
    const float wsc = scale_W[(size_t)u * NH + t];

    // inter-half: acc[m] += w[k] * itT[k][m], all 50 m per thread
    float acc[52];
    #pragma unroll
    for (int m = 0; m < 52; ++m) acc[m] = 0.0f;

    for (int k4 = 0; k4 < 32; ++k4) {
        float4 w4 = *(const float4*)(wrow + NH + k4 * 4);
        float wv[4] = { w4.x, w4.y, w4.z, w4.w };
        #pragma unroll
        for (int kk = 0; kk < 4; ++kk) {
            const float w = wv[kk];
            const float* row = &itT[k4 * 4 + kk][0];
            #pragma unroll
            for (int m4 = 0; m4 < 13; ++m4) {
                float4 v = *(const float4*)(row + m4 * 4);  // uniform -> broadcast
                acc[m4 * 4 + 0] = fmaf(w, v.x, acc[m4 * 4 + 0]);
                acc[m4 * 4 + 1] = fmaf(w, v.y, acc[m4 * 4 + 1]);
                acc[m4 * 4 + 2] = fmaf(w, v.z, acc[m4 * 4 + 2]);
                acc[m4 * 4 + 3] = fmaf(w, v.w, acc[m4 * 4 + 3]);
            }
        }
    }

    // e[m] = sum_h wsc_h * tanh(acc_a_h + acc_h[m]); reduce over 128 threads
    #pragma unroll
    for (int m = 0; m < NM; ++m) {
        float val = wsc * fast_tanh(acc_a + acc[m]);
        #pragma unroll
        for (int s = 1; s < 64; s <<= 1) val += __shfl_xor(val, s);
        if ((t & 63) == 0) atomicAdd(&e_sm[m], val);
    }
    __syncthreads();

    // softmax over m; scale_b is a per-batch constant -> softmax-invariant
    if (t < 64) {
        float x = (t < NM) ? e_sm[t] : -INFINITY;
        float mx = x;
        #pragma unroll
        for (int s = 1; s < 64; s <<= 1) mx = fmaxf(mx, __shfl_xor(mx, s));
        float ex = (t < NM) ? __expf(x - mx) : 0.0f;
        float sum = ex;
        #pragma unroll
        for (int s = 1; s < 64; s <<= 1) sum += __shfl_xor(sum, s);
        float aw = ex / sum;
        attn_sm[t] = aw;
        if (t < NM) attn_out[(size_t)b * NM + t] = aw;
    }
    __syncthreads();

    float c = 0.0f;
    #pragma unroll
    for (int m = 0; m < NM; ++m) c = fmaf(attn_sm[m], itT[t][m], c);
    context[(size_t)b * NH + t] = c;
}

// ---------------- Kernel 2: GRU cell (4 batches / block) ----------------
__global__ __launch_bounds__(128) void gru_kernel(
    const float* __restrict__ emb, const float* __restrict__ hidden,
    const float* __restrict__ context,
    const float* __restrict__ w_ih, const float* __restrict__ w_hh,
    const float* __restrict__ b_ih, const float* __restrict__ b_hh,
    float* __restrict__ out_h, float* __restrict__ out_emb, float* __restrict__ out_gru)
{
    const int b0 = blockIdx.x * 4;
    const int t  = threadIdx.x;

    __shared__ float x_sm[4][2 * NH];
    __shared__ float h_sm[4][NH];
    #pragma unroll
    for (int bb = 0; bb < 4; ++bb) {
        x_sm[bb][t]      = emb[(size_t)(b0 + bb) * NH + t];
        x_sm[bb][NH + t] = context[(size_t)(b0 + bb) * NH + t];
        h_sm[bb][t]      = hidden[(size_t)(b0 + bb) * NH + t];
    }
    __syncthreads();

    const float* wr = w_ih + (size_t)t * 256;
    const float* wz = w_ih + (size_t)(NH + t) * 256;
    const float* wn = w_ih + (size_t)(2 * NH + t) * 256;
    float gr[4], gz[4], gn[4];
    #pragma unroll
    for (int bb = 0; bb < 4; ++bb) { gr[bb] = b_ih[t]; gz[bb] = b_ih[NH + t]; gn[bb] = b_ih[2 * NH + t]; }
    for (int i4 = 0; i4 < 64; ++i4) {
        float4 wr4 = *(const float4*)(wr + i4 * 4);
        float4 wz4 = *(const float4*)(wz + i4 * 4);
        float4 wn4 = *(const float4*)(wn + i4 * 4);
        #pragma unroll
        for (int bb = 0; bb < 4; ++bb) {
            float4 x4 = *(const float4*)(&x_sm[bb][i4 * 4]);
            gr[bb] += wr4.x * x4.x + wr4.y * x4.y + wr4.z * x4.z + wr4.w * x4.w;
            gz[bb] += wz4.x * x4.x + wz4.y * x4.y + wz4.z * x4.z + wz4.w * x4.w;
            gn[bb] += wn4.x * x4.x + wn4.y * x4.y + wn4.z * x4.z + wn4.w * x4.w;
        }
    }
    const float* vr = w_hh + (size_t)t * NH;
    const float* vz = w_hh + (size_t)(NH + t) * NH;
    const float* vn = w_hh + (size_t)(2 * NH + t) * NH;
    float hr[4], hz[4], hn[4];
    #pragma unroll
    for (int bb = 0; bb < 4; ++bb) { hr[bb] = b_hh[t]; hz[bb] = b_hh[NH + t]; hn[bb] = b_hh[2 * NH + t]; }
    for (int i4 = 0; i4 < 32; ++i4) {
        float4 vr4 = *(const float4*)(vr + i4 * 4);
        float4 vz4 = *(const float4*)(vz + i4 * 4);
        float4 vn4 = *(const float4*)(vn + i4 * 4);
        #pragma unroll
        for (int bb = 0; bb < 4; ++bb) {
            float4 h4 = *(const float4*)(&h_sm[bb][i4 * 4]);
            hr[bb] += vr4.x * h4.x + vr4.y * h4.y + vr4.z * h4.z + vr4.w * h4.w;
            hz[bb] += vz4.x * h4.x + vz4.y * h4.y + vz4.z * h4.z + vz4.w * h4.w;
            hn[bb] += vn4.x * h4.x + vn4.y * h4.y + vn4.z * h4.z + vn4.w * h4.w;
        }
    }
    #pragma unroll
    for (int bb = 0; bb < 4; ++bb) {
        float r = fast_sigmoid(gr[bb] + hr[bb]);
        float z = fast_sigmoid(gz[bb] + hz[bb]);
        float n = fast_tanh(gn[bb] + r * hn[bb]);
        float h0 = h_sm[bb][t];
        float hnew = (1.0f - z) * n + z * h0;
        size_t o = (size_t)(b0 + bb) * NH + t;
        out_h[o]   = hnew;
        out_gru[o] = hnew;
        out_emb[o] = x_sm[bb][t];
    }
}

// ---------------- Kernel 3: output projection, bf16 MFMA ----------------
// C(b,n) = sum_k hnew[b][k] * lin_W[n][k] + lin_b[n]
// Block: BM=64 x BN=256, 4 waves of 64m x 64n. A staged in LDS bf16;
// W converted f32->bf16 in-register (L2/L3-resident).
__global__ __launch_bounds__(256) void out_mfma(
    const float* __restrict__ hnew,   // (B,H)
    const float* __restrict__ lin_W,  // (NI,H)
    const float* __restrict__ lin_b,  // (NI,)
    float* __restrict__ out)          // (B,NI)
{
    const int mb   = blockIdx.x;      // m fastest: 16 m-blocks of one n-panel co-dispatch
    const int nb   = blockIdx.y;
    const int tid  = threadIdx.x;
    const int lane = tid & 63;
    const int wave = tid >> 6;

    const int b0 = mb * 64;
    const int n0 = nb * 256 + wave * 64;

    __shared__ __align__(16) unsigned short As[64 * 128];   // bf16, 16KB

    // stage A = hnew tile, f32 -> bf16
    for (int c = tid; c < 1024; c += 256) {       // 1024 chunks of 8 elems
        int r = c >> 4;
        int s = c & 15;
        const float* src = hnew + (size_t)(b0 + r) * NH + s * 8;
        float4 f0 = *(const float4*)(src);
        float4 f1 = *(const float4*)(src + 4);
        bf16x8 p;
        p[0] = (short)f2bf(f0.x); p[1] = (short)f2bf(f0.y);
        p[2] = (short)f2bf(f0.z); p[3] = (short)f2bf(f0.w);
        p[4] = (short)f2bf(f1.x); p[5] = (short)f2bf(f1.y);
        p[6] = (short)f2bf(f1.z); p[7] = (short)f2bf(f1.w);
        *reinterpret_cast<bf16x8*>(&As[r * 128 + s * 8]) = p;
    }
    __syncthreads();

    const int lrow = lane & 15;
    const int lk   = (lane >> 4) * 8;

    // A fragments: a[mf][ks], lane holds A[mf*16+lrow][ks*32+lk .. +8]
    bf16x8 a[4][4];
    #pragma unroll
    for (int mf = 0; mf < 4; ++mf)
        #pragma unroll
        for (int ks = 0; ks < 4; ++ks)
            a[mf][ks] = *reinterpret_cast<const bf16x8*>(&As[(mf * 16 + lrow) * 128 + ks * 32 + lk]);

    f32x4 acc[4][4];
    #pragma unroll
    for (int mf = 0; mf < 4; ++mf)
        #pragma unroll
        for (int nf = 0; nf < 4; ++nf)
            acc[mf][nf] = (f32x4){0.0f, 0.0f, 0.0f, 0.0f};

    float bias[4];
    #pragma unroll
    for (int nf = 0; nf < 4; ++nf) {
        int n = n0 + nf * 16 + lrow;
        bias[nf] = (n < NI) ? lin_b[n] : 0.0f;
    }

    #pragma unroll
    for (int nf = 0; nf < 4; ++nf) {
        int n = n0 + nf * 16 + lrow;
        const float* wr = lin_W + (size_t)(n < NI ? n : 0) * NH + lk;
        bf16x8 bfrag[4];
        #pragma unroll
        for (int ks = 0; ks < 4; ++ks) {
            float4 f0 = *(const float4*)(wr + ks * 32);
            float4 f1 = *(const float4*)(wr + ks * 32 + 4);
            bf16x8 p;
            p[0] = (short)f2bf(f0.x); p[1] = (short)f2bf(f0.y);
            p[2] = (short)f2bf(f0.z); p[3] = (short)f2bf(f0.w);
            p[4] = (short)f2bf(f1.x); p[5] = (short)f2bf(f1.y);
            p[6] = (short)f2bf(f1.z); p[7] = (short)f2bf(f1.w);
            bfrag[ks] = p;
        }
        #pragma unroll
        for (int ks = 0; ks < 4; ++ks)
            #pragma unroll
            for (int mf = 0; mf < 4; ++mf)
                acc[mf][nf] = __builtin_amdgcn_mfma_f32_16x16x32_bf16(
                    a[mf][ks], bfrag[ks], acc[mf][nf], 0, 0, 0);
    }

    // C/D: col(n) = lane&15, row(m) = (lane>>4)*4 + j
    #pragma unroll
    for (int mf = 0; mf < 4; ++mf) {
        #pragma unroll
        for (int nf = 0; nf < 4; ++nf) {
            int n = n0 + nf * 16 + lrow;
            if (n < NI) {
                #pragma unroll
                for (int j = 0; j < 4; ++j) {
                    int m = mf * 16 + (lane >> 4) * 4 + j;
                    out[(size_t)(b0 + m) * NI + n] = acc[mf][nf][j] + bias[nf];
                }
            }
        }
    }
}

extern "C" void kernel_launch(void* const* d_in, const int* in_sizes, int n_in,
                              void* d_out, int out_size, void* d_ws, size_t ws_size,
                              hipStream_t stream) {
    const float* emb      = (const float*)d_in[0];
    const float* hidden   = (const float*)d_in[1];
    const float* inter    = (const float*)d_in[2];
    // d_in[3] = delta_t_h : unused by the reference
    const int*   user     = (const int*)  d_in[4];
    const float* w_ih     = (const float*)d_in[5];
    const float* w_hh     = (const float*)d_in[6];
    const float* b_ih     = (const float*)d_in[7];
    const float* b_hh     = (const float*)d_in[8];
    const float* lin_W    = (const float*)d_in[9];
    const float* lin_b    = (const float*)d_in[10];
    const float* cat_W    = (const float*)d_in[11];
    const float* cat_b    = (const float*)d_in[12];
    const float* scale_W  = (const float*)d_in[13];
    // d_in[14] = scale_b : per-batch constant energy shift -> softmax invariant

    float* out = (float*)d_out;
    float* ctx = (float*)d_ws;   // (B,H) context scratch (512KB)

    attn_kernel<<<NB, 128, 0, stream>>>(hidden, inter, user, cat_W, cat_b, scale_W,
                                        out + OFF_ATT, ctx);
    gru_kernel<<<NB / 4, 128, 0, stream>>>(emb, hidden, ctx, w_ih, w_hh, b_ih, b_hh,
                                           out + OFF_H, out + OFF_EMB, out + OFF_GRU);
    out_mfma<<<dim3(16, (NI + 255) / 256), 256, 0, stream>>>(out + OFF_H, lin_W, lin_b, out);
}

// Round 3
// 286.404 us; speedup vs baseline: 3.2862x; 1.1996x over previous
//
#include <hip/hip_runtime.h>
#include <math.h>

#define NB 1024
#define NM 50
#define NH 128
#define NI 100000

// flat output offsets (return order)
constexpr size_t OFF_H   = (size_t)NB * NI;              // h_new[None]  (1,B,H)
constexpr size_t OFF_EMB = OFF_H   + (size_t)NB * NH;    // embedded_input (B,1,E)
constexpr size_t OFF_GRU = OFF_EMB + (size_t)NB * NH;    // gru_output (B,1,H)
constexpr size_t OFF_ATT = OFF_GRU + (size_t)NB * NH;    // attn_weights (B,M)

typedef __attribute__((ext_vector_type(8))) short bf16x8;
typedef __attribute__((ext_vector_type(4))) float f32x4;

static __device__ __forceinline__ unsigned short f2bf(float x) {
    unsigned int u = __float_as_uint(x);
    return (unsigned short)((u + 0x7FFFu + ((u >> 16) & 1u)) >> 16);   // RNE
}
static __device__ __forceinline__ float fast_tanh(float x) {
    float cx = fminf(fmaxf(x, -15.0f), 15.0f);
    float e = __expf(2.0f * cx);
    return (e - 1.0f) / (e + 1.0f);
}
static __device__ __forceinline__ float fast_sigmoid(float x) {
    float cx = fminf(fmaxf(x, -30.0f), 30.0f);
    return 1.0f / (1.0f + __expf(-cx));
}

// ---------------- Kernel 0: lin_W f32 -> bf16 pre-convert ----------------
__global__ __launch_bounds__(256) void convW_kernel(
    const float* __restrict__ W, unsigned short* __restrict__ Wbf)
{
    const int n8 = NI * NH / 8;   // 1.6M chunks of 8
    for (int i = blockIdx.x * 256 + threadIdx.x; i < n8; i += gridDim.x * 256) {
        const float* s = W + (size_t)i * 8;
        float4 f0 = *(const float4*)(s);
        float4 f1 = *(const float4*)(s + 4);
        bf16x8 p;
        p[0] = (short)f2bf(f0.x); p[1] = (short)f2bf(f0.y);
        p[2] = (short)f2bf(f0.z); p[3] = (short)f2bf(f0.w);
        p[4] = (short)f2bf(f1.x); p[5] = (short)f2bf(f1.y);
        p[6] = (short)f2bf(f1.z); p[7] = (short)f2bf(f1.w);
        *reinterpret_cast<bf16x8*>(Wbf + (size_t)i * 8) = p;
    }
}

// ---------------- Kernel 1: attention (per-batch) ----------------
__global__ __launch_bounds__(128) void attn_kernel(
    const float* __restrict__ hidden,     // (1,B,H)
    const float* __restrict__ inter,      // (B,M,H)
    const int*   __restrict__ user_list,  // (B,)
    const float* __restrict__ cat_W,      // (U,H,2H)
    const float* __restrict__ cat_b,      // (U,H)
    const float* __restrict__ scale_W,    // (U,1,H)
    float* __restrict__ attn_out,         // (B,M)
    float* __restrict__ context)          // (B,H) scratch
{
    const int b = blockIdx.x;
    const int t = threadIdx.x;

    __shared__ float hid[NH];
    __shared__ float itT[NH][52];
    __shared__ float e_sm[64];
    __shared__ float attn_sm[64];

    const int u = user_list[b];

    hid[t] = hidden[b * NH + t];
    for (int idx = t; idx < NM * NH; idx += 128) {
        int m = idx >> 7, j = idx & 127;
        itT[j][m] = inter[(size_t)b * NM * NH + idx];
    }
    itT[t][50] = 0.0f;
    itT[t][51] = 0.0f;
    if (t < 64) e_sm[t] = 0.0f;
    __syncthreads();

    const float* wrow = cat_W + ((size_t)u * NH + t) * (2 * NH);
    float acc_a = cat_b[(size_t)u * NH + t];
    #pragma unroll
    for (int i4 = 0; i4 < NH / 4; ++i4) {
        float4 w  = *(const float4*)(wrow + i4 * 4);
        float4 h4 = *(const float4*)(&hid[i4 * 4]);
        acc_a += w.x * h4.x + w.y * h4.y + w.z * h4.z + w.w * h4.w;
    }
    const float wsc = scale_W[(size_t)u * NH + t];

    float acc[52];
    #pragma unroll
    for (int m = 0; m < 52; ++m) acc[m] = 0.0f;

    for (int k4 = 0; k4 < 32; ++k4) {
        float4 w4 = *(const float4*)(wrow + NH + k4 * 4);
        float wv[4] = { w4.x, w4.y, w4.z, w4.w };
        #pragma unroll
        for (int kk = 0; kk < 4; ++kk) {
            const float w = wv[kk];
            const float* row = &itT[k4 * 4 + kk][0];
            #pragma unroll
            for (int m4 = 0; m4 < 13; ++m4) {
                float4 v = *(const float4*)(row + m4 * 4);
                acc[m4 * 4 + 0] = fmaf(w, v.x, acc[m4 * 4 + 0]);
                acc[m4 * 4 + 1] = fmaf(w, v.y, acc[m4 * 4 + 1]);
                acc[m4 * 4 + 2] = fmaf(w, v.z, acc[m4 * 4 + 2]);
                acc[m4 * 4 + 3] = fmaf(w, v.w, acc[m4 * 4 + 3]);
            }
        }
    }

    #pragma unroll
    for (int m = 0; m < NM; ++m) {
        float val = wsc * fast_tanh(acc_a + acc[m]);
        #pragma unroll
        for (int s = 1; s < 64; s <<= 1) val += __shfl_xor(val, s);
        if ((t & 63) == 0) atomicAdd(&e_sm[m], val);
    }
    __syncthreads();

    if (t < 64) {
        float x = (t < NM) ? e_sm[t] : -INFINITY;
        float mx = x;
        #pragma unroll
        for (int s = 1; s < 64; s <<= 1) mx = fmaxf(mx, __shfl_xor(mx, s));
        float ex = (t < NM) ? __expf(x - mx) : 0.0f;
        float sum = ex;
        #pragma unroll
        for (int s = 1; s < 64; s <<= 1) sum += __shfl_xor(sum, s);
        float aw = ex / sum;
        attn_sm[t] = aw;
        if (t < NM) attn_out[(size_t)b * NM + t] = aw;
    }
    __syncthreads();

    float c = 0.0f;
    #pragma unroll
    for (int m = 0; m < NM; ++m) c = fmaf(attn_sm[m], itT[t][m], c);
    context[(size_t)b * NH + t] = c;
}

// ---------------- Kernel 2: GRU cell (4 batches / block) ----------------
__global__ __launch_bounds__(128) void gru_kernel(
    const float* __restrict__ emb, const float* __restrict__ hidden,
    const float* __restrict__ context,
    const float* __restrict__ w_ih, const float* __restrict__ w_hh,
    const float* __restrict__ b_ih, const float* __restrict__ b_hh,
    float* __restrict__ out_h, float* __restrict__ out_emb, float* __restrict__ out_gru)
{
    const int b0 = blockIdx.x * 4;
    const int t  = threadIdx.x;

    __shared__ float x_sm[4][2 * NH];
    __shared__ float h_sm[4][NH];
    #pragma unroll
    for (int bb = 0; bb < 4; ++bb) {
        x_sm[bb][t]      = emb[(size_t)(b0 + bb) * NH + t];
        x_sm[bb][NH + t] = context[(size_t)(b0 + bb) * NH + t];
        h_sm[bb][t]      = hidden[(size_t)(b0 + bb) * NH + t];
    }
    __syncthreads();

    const float* wr = w_ih + (size_t)t * 256;
    const float* wz = w_ih + (size_t)(NH + t) * 256;
    const float* wn = w_ih + (size_t)(2 * NH + t) * 256;
    float gr[4], gz[4], gn[4];
    #pragma unroll
    for (int bb = 0; bb < 4; ++bb) { gr[bb] = b_ih[t]; gz[bb] = b_ih[NH + t]; gn[bb] = b_ih[2 * NH + t]; }
    for (int i4 = 0; i4 < 64; ++i4) {
        float4 wr4 = *(const float4*)(wr + i4 * 4);
        float4 wz4 = *(const float4*)(wz + i4 * 4);
        float4 wn4 = *(const float4*)(wn + i4 * 4);
        #pragma unroll
        for (int bb = 0; bb < 4; ++bb) {
            float4 x4 = *(const float4*)(&x_sm[bb][i4 * 4]);
            gr[bb] += wr4.x * x4.x + wr4.y * x4.y + wr4.z * x4.z + wr4.w * x4.w;
            gz[bb] += wz4.x * x4.x + wz4.y * x4.y + wz4.z * x4.z + wz4.w * x4.w;
            gn[bb] += wn4.x * x4.x + wn4.y * x4.y + wn4.z * x4.z + wn4.w * x4.w;
        }
    }
    const float* vr = w_hh + (size_t)t * NH;
    const float* vz = w_hh + (size_t)(NH + t) * NH;
    const float* vn = w_hh + (size_t)(2 * NH + t) * NH;
    float hr[4], hz[4], hn[4];
    #pragma unroll
    for (int bb = 0; bb < 4; ++bb) { hr[bb] = b_hh[t]; hz[bb] = b_hh[NH + t]; hn[bb] = b_hh[2 * NH + t]; }
    for (int i4 = 0; i4 < 32; ++i4) {
        float4 vr4 = *(const float4*)(vr + i4 * 4);
        float4 vz4 = *(const float4*)(vz + i4 * 4);
        float4 vn4 = *(const float4*)(vn + i4 * 4);
        #pragma unroll
        for (int bb = 0; bb < 4; ++bb) {
            float4 h4 = *(const float4*)(&h_sm[bb][i4 * 4]);
            hr[bb] += vr4.x * h4.x + vr4.y * h4.y + vr4.z * h4.z + vr4.w * h4.w;
            hz[bb] += vz4.x * h4.x + vz4.y * h4.y + vz4.z * h4.z + vz4.w * h4.w;
            hn[bb] += vn4.x * h4.x + vn4.y * h4.y + vn4.z * h4.z + vn4.w * h4.w;
        }
    }
    #pragma unroll
    for (int bb = 0; bb < 4; ++bb) {
        float r = fast_sigmoid(gr[bb] + hr[bb]);
        float z = fast_sigmoid(gz[bb] + hz[bb]);
        float n = fast_tanh(gn[bb] + r * hn[bb]);
        float h0 = h_sm[bb][t];
        float hnew = (1.0f - z) * n + z * h0;
        size_t o = (size_t)(b0 + bb) * NH + t;
        out_h[o]   = hnew;
        out_gru[o] = hnew;
        out_emb[o] = x_sm[bb][t];
    }
}

// ---------------- Kernel 3: output projection, bf16 MFMA ----------------
// PRE=true: B-frags are direct 16B loads from pre-converted bf16 W.
// Epilogue: stage 16x256 C-slabs in LDS (reusing the A buffer), store 1KB
// contiguous per wave instruction.
template<bool PRE>
__global__ __launch_bounds__(256) void out_mfma(
    const float* __restrict__ hnew,           // (B,H)
    const float* __restrict__ lin_W,          // (NI,H) f32
    const unsigned short* __restrict__ Wbf,   // (NI,H) bf16 (PRE only)
    const float* __restrict__ lin_b,          // (NI,)
    float* __restrict__ out)                  // (B,NI)
{
    const int mb   = blockIdx.x;   // m fastest: m-blocks of one n-panel co-dispatch
    const int nb   = blockIdx.y;
    const int tid  = threadIdx.x;
    const int lane = tid & 63;
    const int wave = tid >> 6;

    const int b0 = mb * 64;
    const int n0 = nb * 256 + wave * 64;

    __shared__ __align__(16) unsigned char smem[16 * 260 * 4];   // 16.6KB
    unsigned short* As = (unsigned short*)smem;                  // [64][128] bf16
    float (*Cs)[260]   = (float(*)[260])smem;                    // [16][260] f32

    // stage A = hnew tile, f32 -> bf16
    for (int c = tid; c < 1024; c += 256) {
        int r = c >> 4;
        int s = c & 15;
        const float* src = hnew + (size_t)(b0 + r) * NH + s * 8;
        float4 f0 = *(const float4*)(src);
        float4 f1 = *(const float4*)(src + 4);
        bf16x8 p;
        p[0] = (short)f2bf(f0.x); p[1] = (short)f2bf(f0.y);
        p[2] = (short)f2bf(f0.z); p[3] = (short)f2bf(f0.w);
        p[4] = (short)f2bf(f1.x); p[5] = (short)f2bf(f1.y);
        p[6] = (short)f2bf(f1.z); p[7] = (short)f2bf(f1.w);
        *reinterpret_cast<bf16x8*>(&As[r * 128 + s * 8]) = p;
    }
    __syncthreads();

    const int lrow = lane & 15;
    const int lk   = (lane >> 4) * 8;

    bf16x8 a[4][4];
    #pragma unroll
    for (int mf = 0; mf < 4; ++mf)
        #pragma unroll
        for (int ks = 0; ks < 4; ++ks)
            a[mf][ks] = *reinterpret_cast<const bf16x8*>(&As[(mf * 16 + lrow) * 128 + ks * 32 + lk]);

    f32x4 acc[4][4];
    #pragma unroll
    for (int mf = 0; mf < 4; ++mf)
        #pragma unroll
        for (int nf = 0; nf < 4; ++nf)
            acc[mf][nf] = (f32x4){0.0f, 0.0f, 0.0f, 0.0f};

    float bias[4];
    #pragma unroll
    for (int nf = 0; nf < 4; ++nf) {
        int n = n0 + nf * 16 + lrow;
        bias[nf] = (n < NI) ? lin_b[n] : 0.0f;
    }

    #pragma unroll
    for (int nf = 0; nf < 4; ++nf) {
        int n = n0 + nf * 16 + lrow;
        const size_t nrow = (size_t)(n < NI ? n : 0) * NH;
        bf16x8 bfrag[4];
        if (PRE) {
            const unsigned short* wp = Wbf + nrow + lk;
            #pragma unroll
            for (int ks = 0; ks < 4; ++ks)
                bfrag[ks] = *reinterpret_cast<const bf16x8*>(wp + ks * 32);
        } else {
            const float* wr = lin_W + nrow + lk;
            #pragma unroll
            for (int ks = 0; ks < 4; ++ks) {
                float4 f0 = *(const float4*)(wr + ks * 32);
                float4 f1 = *(const float4*)(wr + ks * 32 + 4);
                bf16x8 p;
                p[0] = (short)f2bf(f0.x); p[1] = (short)f2bf(f0.y);
                p[2] = (short)f2bf(f0.z); p[3] = (short)f2bf(f0.w);
                p[4] = (short)f2bf(f1.x); p[5] = (short)f2bf(f1.y);
                p[6] = (short)f2bf(f1.z); p[7] = (short)f2bf(f1.w);
                bfrag[ks] = p;
            }
        }
        #pragma unroll
        for (int ks = 0; ks < 4; ++ks)
            #pragma unroll
            for (int mf = 0; mf < 4; ++mf)
                acc[mf][nf] = __builtin_amdgcn_mfma_f32_16x16x32_bf16(
                    a[mf][ks], bfrag[ks], acc[mf][nf], 0, 0, 0);
    }

    // epilogue: per 16-row slab, LDS transpose then 1KB-contiguous row stores
    const int g = lane >> 4;   // row group 0..3
    #pragma unroll
    for (int mf = 0; mf < 4; ++mf) {
        __syncthreads();   // previous slab fully read (and As fully consumed)
        #pragma unroll
        for (int nf = 0; nf < 4; ++nf) {
            int col = wave * 64 + nf * 16 + lrow;
            #pragma unroll
            for (int j = 0; j < 4; ++j)
                Cs[g * 4 + j][col] = acc[mf][nf][j] + bias[nf];
        }
        __syncthreads();
        #pragma unroll
        for (int p = 0; p < 4; ++p) {
            int r    = p * 4 + (tid >> 6);
            int col4 = (tid & 63) * 4;
            int n    = nb * 256 + col4;
            if (n < NI) {
                float4 v = *(const float4*)(&Cs[r][col4]);
                *(float4*)(&out[(size_t)(b0 + mf * 16 + r) * NI + n]) = v;
            }
        }
    }
}

extern "C" void kernel_launch(void* const* d_in, const int* in_sizes, int n_in,
                              void* d_out, int out_size, void* d_ws, size_t ws_size,
                              hipStream_t stream) {
    const float* emb      = (const float*)d_in[0];
    const float* hidden   = (const float*)d_in[1];
    const float* inter    = (const float*)d_in[2];
    // d_in[3] = delta_t_h : unused by the reference
    const int*   user     = (const int*)  d_in[4];
    const float* w_ih     = (const float*)d_in[5];
    const float* w_hh     = (const float*)d_in[6];
    const float* b_ih     = (const float*)d_in[7];
    const float* b_hh     = (const float*)d_in[8];
    const float* lin_W    = (const float*)d_in[9];
    const float* lin_b    = (const float*)d_in[10];
    const float* cat_W    = (const float*)d_in[11];
    const float* cat_b    = (const float*)d_in[12];
    const float* scale_W  = (const float*)d_in[13];
    // d_in[14] = scale_b : per-batch constant energy shift -> softmax invariant

    float* out = (float*)d_out;
    float* ctx = (float*)d_ws;                               // (B,H) f32, 512KB
    unsigned short* Wbf = (unsigned short*)((char*)d_ws + 512 * 1024);
    const size_t need = 512 * 1024 + (size_t)NI * NH * 2;    // ~26.1 MB
    const bool pre = (ws_size >= need);

    if (pre)
        convW_kernel<<<2048, 256, 0, stream>>>(lin_W, Wbf);

    attn_kernel<<<NB, 128, 0, stream>>>(hidden, inter, user, cat_W, cat_b, scale_W,
                                        out + OFF_ATT, ctx);
    gru_kernel<<<NB / 4, 128, 0, stream>>>(emb, hidden, ctx, w_ih, w_hh, b_ih, b_hh,
                                           out + OFF_H, out + OFF_EMB, out + OFF_GRU);
    if (pre)
        out_mfma<true><<<dim3(16, (NI + 255) / 256), 256, 0, stream>>>(
            out + OFF_H, lin_W, Wbf, lin_b, out);
    else
        out_mfma<false><<<dim3(16, (NI + 255) / 256), 256, 0, stream>>>(
            out + OFF_H, lin_W, nullptr, lin_b, out);
}

// Round 5
// 209.463 us; speedup vs baseline: 4.4934x; 1.3673x over previous
//
#include <hip/hip_runtime.h>
#include <math.h>

#define NB 1024
#define NM 50
#define NH 128
#define NI 100000

// flat output offsets (return order)
constexpr size_t OFF_H   = (size_t)NB * NI;              // h_new[None]  (1,B,H)
constexpr size_t OFF_EMB = OFF_H   + (size_t)NB * NH;    // embedded_input (B,1,E)
constexpr size_t OFF_GRU = OFF_EMB + (size_t)NB * NH;    // gru_output (B,1,H)
constexpr size_t OFF_ATT = OFF_GRU + (size_t)NB * NH;    // attn_weights (B,M)

typedef __attribute__((ext_vector_type(8))) short bf16x8;
typedef __attribute__((ext_vector_type(4))) float f32x4;

static __device__ __forceinline__ unsigned short f2bf(float x) {
    unsigned int u = __float_as_uint(x);
    return (unsigned short)((u + 0x7FFFu + ((u >> 16) & 1u)) >> 16);   // RNE
}
static __device__ __forceinline__ float bf2f(unsigned short v) {
    return __uint_as_float((unsigned int)v << 16);
}
static __device__ __forceinline__ float fast_tanh(float x) {
    float cx = fminf(fmaxf(x, -15.0f), 15.0f);
    float e = __expf(2.0f * cx);
    return (e - 1.0f) / (e + 1.0f);
}
static __device__ __forceinline__ float fast_sigmoid(float x) {
    float cx = fminf(fmaxf(x, -30.0f), 30.0f);
    return 1.0f / (1.0f + __expf(-cx));
}
static __device__ __forceinline__ bf16x8 pack8(float4 f0, float4 f1) {
    bf16x8 p;
    p[0] = (short)f2bf(f0.x); p[1] = (short)f2bf(f0.y);
    p[2] = (short)f2bf(f0.z); p[3] = (short)f2bf(f0.w);
    p[4] = (short)f2bf(f1.x); p[5] = (short)f2bf(f1.y);
    p[6] = (short)f2bf(f1.z); p[7] = (short)f2bf(f1.w);
    return p;
}

// ---------------- Kernel 0: lin_W f32 -> bf16 pre-convert ----------------
__global__ __launch_bounds__(256) void convW_kernel(
    const float* __restrict__ W, unsigned short* __restrict__ Wbf)
{
    const int n8 = NI * NH / 8;
    for (int i = blockIdx.x * 256 + threadIdx.x; i < n8; i += gridDim.x * 256) {
        const float* s = W + (size_t)i * 8;
        bf16x8 p = pack8(*(const float4*)s, *(const float4*)(s + 4));
        __builtin_nontemporal_store(p, reinterpret_cast<bf16x8*>(Wbf + (size_t)i * 8));
    }
}

// ---------------- Kernel 1: attention via MFMA (1 block = 1 batch) ------
// C[m][h] = tanh( [hid|inter][m,:] . cat_W[u][h,:] + cat_b[u][h] )
// e[m] = C[m,:] . scale_W[u]; softmax; context = attn^T @ inter
__global__ __launch_bounds__(256) void attn_mfma(
    const float* __restrict__ hidden,     // (1,B,H)
    const float* __restrict__ inter,      // (B,M,H)
    const int*   __restrict__ user_list,  // (B,)
    const float* __restrict__ cat_W,      // (U,H,2H)
    const float* __restrict__ cat_b,      // (U,H)
    const float* __restrict__ scale_W,    // (U,1,H)
    float* __restrict__ attn_out,         // (B,M)
    float* __restrict__ context)          // (B,H) scratch
{
    const int b    = blockIdx.x;
    const int tid  = threadIdx.x;
    const int lane = tid & 63;
    const int wave = tid >> 6;

    __shared__ __align__(16) unsigned short A[64 * 256];  // swizzled [m][k], 32KB
    __shared__ float e_sm[64];
    __shared__ float attn_sm[64];

    const int u = user_list[b];

    // stage A rows: cols 0-127 = hidden[b], cols 128-255 = inter[b][m] (m<50), else 0
    for (int c = tid; c < 2048; c += 256) {
        int r = c >> 5, s = c & 31;            // row, 8-elem col chunk
        float4 f0, f1;
        if (s < 16) {
            const float* src = hidden + (size_t)b * NH + s * 8;
            f0 = *(const float4*)src; f1 = *(const float4*)(src + 4);
        } else if (r < NM) {
            const float* src = inter + ((size_t)b * NM + r) * NH + (s - 16) * 8;
            f0 = *(const float4*)src; f1 = *(const float4*)(src + 4);
        } else {
            f0 = (float4){0,0,0,0}; f1 = f0;
        }
        int byte = (r * 512 + s * 16) ^ ((r & 7) << 4);
        *reinterpret_cast<bf16x8*>((char*)A + byte) = pack8(f0, f1);
    }
    if (tid < 64) e_sm[tid] = 0.0f;
    __syncthreads();

    const int lrow = lane & 15;
    const int lk8  = (lane >> 4) * 8;          // k sub-offset (elements)

    // per-lane h columns this wave owns: h = wave*32 + nf*16 + lrow
    float bc[2], ws[2];
    #pragma unroll
    for (int nf = 0; nf < 2; ++nf) {
        int h = wave * 32 + nf * 16 + lrow;
        bc[nf] = cat_b[(size_t)u * NH + h];
        ws[nf] = scale_W[(size_t)u * NH + h];
    }

    f32x4 acc[4][2];
    #pragma unroll
    for (int mf = 0; mf < 4; ++mf)
        #pragma unroll
        for (int nf = 0; nf < 2; ++nf)
            acc[mf][nf] = (f32x4){0,0,0,0};

    #pragma unroll
    for (int ks = 0; ks < 8; ++ks) {           // K = 256 = 8 x 32
        bf16x8 bfr[2];
        #pragma unroll
        for (int nf = 0; nf < 2; ++nf) {
            int h = wave * 32 + nf * 16 + lrow;
            const float* wp = cat_W + ((size_t)u * NH + h) * 256 + ks * 32 + lk8;
            bfr[nf] = pack8(*(const float4*)wp, *(const float4*)(wp + 4));
        }
        #pragma unroll
        for (int mf = 0; mf < 4; ++mf) {
            int row  = mf * 16 + lrow;
            int byte = (row * 512 + ks * 64 + lk8 * 2) ^ ((row & 7) << 4);
            bf16x8 a = *reinterpret_cast<const bf16x8*>((char*)A + byte);
            acc[mf][0] = __builtin_amdgcn_mfma_f32_16x16x32_bf16(a, bfr[0], acc[mf][0], 0, 0, 0);
            acc[mf][1] = __builtin_amdgcn_mfma_f32_16x16x32_bf16(a, bfr[1], acc[mf][1], 0, 0, 0);
        }
    }

    // e[m] partial: tanh(acc+bc)*ws summed over this wave's 32 h, then 16-lane reduce
    #pragma unroll
    for (int mf = 0; mf < 4; ++mf) {
        #pragma unroll
        for (int j = 0; j < 4; ++j) {
            float s = fast_tanh(acc[mf][0][j] + bc[0]) * ws[0]
                    + fast_tanh(acc[mf][1][j] + bc[1]) * ws[1];
            s += __shfl_xor(s, 1); s += __shfl_xor(s, 2);
            s += __shfl_xor(s, 4); s += __shfl_xor(s, 8);
            if (lrow == 0) atomicAdd(&e_sm[mf * 16 + (lane >> 4) * 4 + j], s);
        }
    }
    __syncthreads();

    // softmax over m<50 (scale_b is per-batch constant -> softmax-invariant)
    if (tid < 64) {
        float x = (tid < NM) ? e_sm[tid] : -INFINITY;
        float mx = x;
        #pragma unroll
        for (int s = 1; s < 64; s <<= 1) mx = fmaxf(mx, __shfl_xor(mx, s));
        float ex = (tid < NM) ? __expf(x - mx) : 0.0f;
        float sum = ex;
        #pragma unroll
        for (int s = 1; s < 64; s <<= 1) sum += __shfl_xor(sum, s);
        float aw = ex / sum;
        attn_sm[tid] = aw;
        if (tid < NM) attn_out[(size_t)b * NM + tid] = aw;
    }
    __syncthreads();

    // context[h] = sum_m attn[m] * inter[m][h]  (inter re-read from bf16 A tile)
    if (tid < NH) {
        float c = 0.0f;
        #pragma unroll
        for (int m = 0; m < NM; ++m) {
            int byte = (m * 512 + (NH + tid) * 2) ^ ((m & 7) << 4);
            c = fmaf(attn_sm[m], bf2f(*reinterpret_cast<const unsigned short*>((char*)A + byte)), c);
        }
        context[(size_t)b * NH + tid] = c;
    }
}

// ---------------- Kernel 2: GRU cell (4 batches / block) ----------------
__global__ __launch_bounds__(128) void gru_kernel(
    const float* __restrict__ emb, const float* __restrict__ hidden,
    const float* __restrict__ context,
    const float* __restrict__ w_ih, const float* __restrict__ w_hh,
    const float* __restrict__ b_ih, const float* __restrict__ b_hh,
    float* __restrict__ out_h, float* __restrict__ out_emb, float* __restrict__ out_gru)
{
    const int b0 = blockIdx.x * 4;
    const int t  = threadIdx.x;

    __shared__ float x_sm[4][2 * NH];
    __shared__ float h_sm[4][NH];
    #pragma unroll
    for (int bb = 0; bb < 4; ++bb) {
        x_sm[bb][t]      = emb[(size_t)(b0 + bb) * NH + t];
        x_sm[bb][NH + t] = context[(size_t)(b0 + bb) * NH + t];
        h_sm[bb][t]      = hidden[(size_t)(b0 + bb) * NH + t];
    }
    __syncthreads();

    const float* wr = w_ih + (size_t)t * 256;
    const float* wz = w_ih + (size_t)(NH + t) * 256;
    const float* wn = w_ih + (size_t)(2 * NH + t) * 256;
    float gr[4], gz[4], gn[4];
    #pragma unroll
    for (int bb = 0; bb < 4; ++bb) { gr[bb] = b_ih[t]; gz[bb] = b_ih[NH + t]; gn[bb] = b_ih[2 * NH + t]; }
    for (int i4 = 0; i4 < 64; ++i4) {
        float4 wr4 = *(const float4*)(wr + i4 * 4);
        float4 wz4 = *(const float4*)(wz + i4 * 4);
        float4 wn4 = *(const float4*)(wn + i4 * 4);
        #pragma unroll
        for (int bb = 0; bb < 4; ++bb) {
            float4 x4 = *(const float4*)(&x_sm[bb][i4 * 4]);
            gr[bb] += wr4.x * x4.x + wr4.y * x4.y + wr4.z * x4.z + wr4.w * x4.w;
            gz[bb] += wz4.x * x4.x + wz4.y * x4.y + wz4.z * x4.z + wz4.w * x4.w;
            gn[bb] += wn4.x * x4.x + wn4.y * x4.y + wn4.z * x4.z + wn4.w * x4.w;
        }
    }
    const float* vr = w_hh + (size_t)t * NH;
    const float* vz = w_hh + (size_t)(NH + t) * NH;
    const float* vn = w_hh + (size_t)(2 * NH + t) * NH;
    float hr[4], hz[4], hn[4];
    #pragma unroll
    for (int bb = 0; bb < 4; ++bb) { hr[bb] = b_hh[t]; hz[bb] = b_hh[NH + t]; hn[bb] = b_hh[2 * NH + t]; }
    for (int i4 = 0; i4 < 32; ++i4) {
        float4 vr4 = *(const float4*)(vr + i4 * 4);
        float4 vz4 = *(const float4*)(vz + i4 * 4);
        float4 vn4 = *(const float4*)(vn + i4 * 4);
        #pragma unroll
        for (int bb = 0; bb < 4; ++bb) {
            float4 h4 = *(const float4*)(&h_sm[bb][i4 * 4]);
            hr[bb] += vr4.x * h4.x + vr4.y * h4.y + vr4.z * h4.z + vr4.w * h4.w;
            hz[bb] += vz4.x * h4.x + vz4.y * h4.y + vz4.z * h4.z + vz4.w * h4.w;
            hn[bb] += vn4.x * h4.x + vn4.y * h4.y + vn4.z * h4.z + vn4.w * h4.w;
        }
    }
    #pragma unroll
    for (int bb = 0; bb < 4; ++bb) {
        float r = fast_sigmoid(gr[bb] + hr[bb]);
        float z = fast_sigmoid(gz[bb] + hz[bb]);
        float n = fast_tanh(gn[bb] + r * hn[bb]);
        float h0 = h_sm[bb][t];
        float hnew = (1.0f - z) * n + z * h0;
        size_t o = (size_t)(b0 + bb) * NH + t;
        out_h[o]   = hnew;
        out_gru[o] = hnew;
        out_emb[o] = x_sm[bb][t];
    }
}

// ---------------- Kernel 3: output projection, bf16 MFMA ----------------
// 1-D grid, XCD-chunked remap: panel's 16 m-tiles stay on one XCD's L2.
// As XOR-swizzled (kills 16-way ds_read conflicts). Nontemporal C stores.
template<bool PRE>
__global__ __launch_bounds__(256) void out_mfma(
    const float* __restrict__ hnew,           // (B,H)
    const float* __restrict__ lin_W,          // (NI,H) f32
    const unsigned short* __restrict__ Wbf,   // (NI,H) bf16 (PRE only)
    const float* __restrict__ lin_b,          // (NI,)
    float* __restrict__ out)                  // (B,NI)
{
    const int L  = blockIdx.x;                 // 0..6255 ; 6256 = 8 XCDs * 782
    const int wg = (L & 7) * 782 + (L >> 3);   // bijective chunk-per-XCD remap
    const int mb = wg & 15;
    const int nb = wg >> 4;

    const int tid  = threadIdx.x;
    const int lane = tid & 63;
    const int wave = tid >> 6;

    const int b0 = mb * 64;
    const int n0 = nb * 256 + wave * 64;

    __shared__ __align__(16) unsigned char smem[16 * 260 * 4];   // 16.6KB
    unsigned short* As = (unsigned short*)smem;                  // [64][128] bf16, swizzled
    float (*Cs)[260]   = (float(*)[260])smem;                    // [16][260] f32

    // stage A = hnew tile, f32 -> bf16, XOR-swizzled
    for (int c = tid; c < 1024; c += 256) {
        int r = c >> 4;
        int s = c & 15;
        const float* src = hnew + (size_t)(b0 + r) * NH + s * 8;
        bf16x8 p = pack8(*(const float4*)src, *(const float4*)(src + 4));
        int byte = (r * 256 + s * 16) ^ ((r & 7) << 4);
        *reinterpret_cast<bf16x8*>((char*)As + byte) = p;
    }
    __syncthreads();

    const int lrow = lane & 15;
    const int lk8  = (lane >> 4) * 8;

    bf16x8 a[4][4];
    #pragma unroll
    for (int mf = 0; mf < 4; ++mf)
        #pragma unroll
        for (int ks = 0; ks < 4; ++ks) {
            int row  = mf * 16 + lrow;
            int byte = (row * 256 + ks * 64 + lk8 * 2) ^ ((row & 7) << 4);
            a[mf][ks] = *reinterpret_cast<const bf16x8*>((char*)As + byte);
        }

    f32x4 acc[4][4];
    #pragma unroll
    for (int mf = 0; mf < 4; ++mf)
        #pragma unroll
        for (int nf = 0; nf < 4; ++nf)
            acc[mf][nf] = (f32x4){0,0,0,0};

    float bias[4];
    #pragma unroll
    for (int nf = 0; nf < 4; ++nf) {
        int n = n0 + nf * 16 + lrow;
        bias[nf] = (n < NI) ? lin_b[n] : 0.0f;
    }

    #pragma unroll
    for (int nf = 0; nf < 4; ++nf) {
        int n = n0 + nf * 16 + lrow;
        const size_t nrow = (size_t)(n < NI ? n : 0) * NH;
        bf16x8 bfrag[4];
        if (PRE) {
            const unsigned short* wp = Wbf + nrow + lk8;
            #pragma unroll
            for (int ks = 0; ks < 4; ++ks)
                bfrag[ks] = *reinterpret_cast<const bf16x8*>(wp + ks * 32);
        } else {
            const float* wr = lin_W + nrow + lk8;
            #pragma unroll
            for (int ks = 0; ks < 4; ++ks)
                bfrag[ks] = pack8(*(const float4*)(wr + ks * 32),
                                  *(const float4*)(wr + ks * 32 + 4));
        }
        #pragma unroll
        for (int ks = 0; ks < 4; ++ks)
            #pragma unroll
            for (int mf = 0; mf < 4; ++mf)
                acc[mf][nf] = __builtin_amdgcn_mfma_f32_16x16x32_bf16(
                    a[mf][ks], bfrag[ks], acc[mf][nf], 0, 0, 0);
    }

    // epilogue: per 16-row slab, LDS transpose then contiguous nontemporal stores
    const int g = lane >> 4;
    #pragma unroll
    for (int mf = 0; mf < 4; ++mf) {
        __syncthreads();
        #pragma unroll
        for (int nf = 0; nf < 4; ++nf) {
            int col = wave * 64 + nf * 16 + lrow;
            #pragma unroll
            for (int j = 0; j < 4; ++j)
                Cs[g * 4 + j][col] = acc[mf][nf][j] + bias[nf];
        }
        __syncthreads();
        #pragma unroll
        for (int p = 0; p < 4; ++p) {
            int r    = p * 4 + (tid >> 6);
            int col4 = (tid & 63) * 4;
            int n    = nb * 256 + col4;
            if (n < NI) {
                f32x4 v = *(const f32x4*)(&Cs[r][col4]);
                __builtin_nontemporal_store(v,
                    (f32x4*)(&out[(size_t)(b0 + mf * 16 + r) * NI + n]));
            }
        }
    }
}

extern "C" void kernel_launch(void* const* d_in, const int* in_sizes, int n_in,
                              void* d_out, int out_size, void* d_ws, size_t ws_size,
                              hipStream_t stream) {
    const float* emb      = (const float*)d_in[0];
    const float* hidden   = (const float*)d_in[1];
    const float* inter    = (const float*)d_in[2];
    // d_in[3] = delta_t_h : unused by the reference
    const int*   user     = (const int*)  d_in[4];
    const float* w_ih     = (const float*)d_in[5];
    const float* w_hh     = (const float*)d_in[6];
    const float* b_ih     = (const float*)d_in[7];
    const float* b_hh     = (const float*)d_in[8];
    const float* lin_W    = (const float*)d_in[9];
    const float* lin_b    = (const float*)d_in[10];
    const float* cat_W    = (const float*)d_in[11];
    const float* cat_b    = (const float*)d_in[12];
    const float* scale_W  = (const float*)d_in[13];
    // d_in[14] = scale_b : per-batch constant energy shift -> softmax invariant

    float* out = (float*)d_out;
    float* ctx = (float*)d_ws;                               // (B,H) f32, 512KB
    unsigned short* Wbf = (unsigned short*)((char*)d_ws + 512 * 1024);
    const size_t need = 512 * 1024 + (size_t)NI * NH * 2;    // ~26.1 MB
    const bool pre = (ws_size >= need);

    attn_mfma<<<NB, 256, 0, stream>>>(hidden, inter, user, cat_W, cat_b, scale_W,
                                      out + OFF_ATT, ctx);
    gru_kernel<<<NB / 4, 128, 0, stream>>>(emb, hidden, ctx, w_ih, w_hh, b_ih, b_hh,
                                           out + OFF_H, out + OFF_EMB, out + OFF_GRU);
    if (pre) {
        convW_kernel<<<2048, 256, 0, stream>>>(lin_W, Wbf);
        out_mfma<true><<<6256, 256, 0, stream>>>(out + OFF_H, lin_W, Wbf, lin_b, out);
    } else {
        out_mfma<false><<<6256, 256, 0, stream>>>(out + OFF_H, lin_W, nullptr, lin_b, out);
    }
}